// Round 1
// baseline (18733.722 us; speedup 1.0000x reference)
//
#include <hip/hip_runtime.h>
#include <hip/hip_bf16.h>
#include <stdint.h>
#include <stddef.h>

// Problem constants
#define B_ 4096
#define S_ 64
#define D_ 512
#define DEPTH_ 4

typedef __attribute__((ext_vector_type(8))) __bf16 bf16x8;
typedef __attribute__((ext_vector_type(4))) float f32x4;
typedef __hip_bfloat16 bf16_t;

// ---------------------------------------------------------------------------
// async global->LDS, 16B per lane. LDS dest is wave-uniform base + lane*16.
// ---------------------------------------------------------------------------
__device__ __forceinline__ void async_copy16(const void* g, void* lds) {
  __builtin_amdgcn_global_load_lds(
      (const __attribute__((address_space(1))) void*)g,
      (__attribute__((address_space(3))) void*)lds, 16, 0, 0);
}

// ---------------------------------------------------------------------------
// GEMM: C(M,N) = A(M,K) @ Bt(N,K)^T  (+bias, epilogue variants)
//   A, Bt bf16 row-major (K contiguous). fp32 accumulate in AGPRs.
//   EPI 0: X[row*N+col] += acc + bias   (fp32 residual)
//   EPI 1: O[row*N+col]  = bf16(relu(acc + bias))
// Block: 256 threads = 4 waves in 2x2, wave tile (TM/2)x(TN/2),
// mfma_f32_16x16x32_bf16, BK=64, m97-style 2-barrier K loop.
// ---------------------------------------------------------------------------
template<int TM, int TN, int EPI>
__launch_bounds__(256)
__global__ void gemm_bf16(const bf16_t* __restrict__ A,
                          const bf16_t* __restrict__ Bt,
                          const float* __restrict__ bias,
                          float* __restrict__ X,
                          bf16_t* __restrict__ O,
                          int M, int N, int K)
{
  constexpr int BK  = 64;
  constexpr int WM  = TM / 2, WN = TN / 2;
  constexpr int NMI = WM / 16, NNI = WN / 16;
  constexpr int CA  = TM / 8, CB = TN / 8;   // 1KB chunks (8 rows of 128B)

  __shared__ __align__(16) bf16_t sA[TM * BK];
  __shared__ __align__(16) bf16_t sB[TN * BK];

  const int tid  = threadIdx.x;
  const int lane = tid & 63;
  const int wave = tid >> 6;
  const int wm   = wave & 1;
  const int wn   = wave >> 1;
  const int m0   = blockIdx.x * TM;
  const int n0   = blockIdx.y * TN;

  const int lr = lane >> 3;        // row within 1KB chunk (8 rows)
  const int lc = (lane & 7) * 8;   // bf16 col within row

  f32x4 acc[NMI][NNI];
#pragma unroll
  for (int mi = 0; mi < NMI; ++mi)
#pragma unroll
    for (int ni = 0; ni < NNI; ++ni)
      acc[mi][ni] = (f32x4){0.f, 0.f, 0.f, 0.f};

  for (int k0 = 0; k0 < K; k0 += BK) {
    // stage A tile
#pragma unroll
    for (int c = wave; c < CA; c += 4) {
      const bf16_t* g = A + (size_t)(m0 + c * 8 + lr) * K + (k0 + lc);
      async_copy16(g, (char*)sA + c * 1024);
    }
    // stage B tile
#pragma unroll
    for (int c = wave; c < CB; c += 4) {
      const bf16_t* g = Bt + (size_t)(n0 + c * 8 + lr) * K + (k0 + lc);
      async_copy16(g, (char*)sB + c * 1024);
    }
    __syncthreads();   // drains vmcnt(0) -> LDS ready

#pragma unroll
    for (int kk = 0; kk < BK; kk += 32) {
      bf16x8 af[NMI], bfv[NNI];
#pragma unroll
      for (int mi = 0; mi < NMI; ++mi)
        af[mi] = *(const bf16x8*)&sA[(wm * WM + mi * 16 + (lane & 15)) * BK + kk + (lane >> 4) * 8];
#pragma unroll
      for (int ni = 0; ni < NNI; ++ni)
        bfv[ni] = *(const bf16x8*)&sB[(wn * WN + ni * 16 + (lane & 15)) * BK + kk + (lane >> 4) * 8];
#pragma unroll
      for (int mi = 0; mi < NMI; ++mi)
#pragma unroll
        for (int ni = 0; ni < NNI; ++ni)
          acc[mi][ni] = __builtin_amdgcn_mfma_f32_16x16x32_bf16(af[mi], bfv[ni], acc[mi][ni], 0, 0, 0);
    }
    __syncthreads();   // protect LDS before next stage
  }

  // epilogue. C/D layout (verified m89/m91): col = lane&15, row = (lane>>4)*4 + r
#pragma unroll
  for (int mi = 0; mi < NMI; ++mi) {
#pragma unroll
    for (int ni = 0; ni < NNI; ++ni) {
      const int col  = n0 + wn * WN + ni * 16 + (lane & 15);
      const int row0 = m0 + wm * WM + mi * 16 + ((lane >> 4) << 2);
      const float bv = bias[col];
#pragma unroll
      for (int r = 0; r < 4; ++r) {
        const float v = acc[mi][ni][r] + bv;
        const size_t idx = (size_t)(row0 + r) * N + col;
        if constexpr (EPI == 0) {
          X[idx] += v;
        } else {
          O[idx] = __float2bfloat16(v > 0.f ? v : 0.f);
        }
      }
    }
  }
}

// ---------------------------------------------------------------------------
// LayerNorm helper: v[8] per lane (64 lanes x 8 = 512), write bf16 row
// ---------------------------------------------------------------------------
__device__ __forceinline__ void ln_store(const float v[8],
                                         const float* __restrict__ gamma,
                                         const float* __restrict__ beta,
                                         bf16_t* __restrict__ yrow, int lane)
{
  float s = 0.f, ss = 0.f;
#pragma unroll
  for (int i = 0; i < 8; ++i) { s += v[i]; ss += v[i] * v[i]; }
#pragma unroll
  for (int o = 32; o; o >>= 1) { s += __shfl_xor(s, o); ss += __shfl_xor(ss, o); }
  const float m   = s * (1.f / D_);
  const float inv = rsqrtf(ss * (1.f / D_) - m * m + 1e-5f);
  const int c0 = lane * 8;
  float g[8], b[8];
  *(float4*)&g[0] = *(const float4*)&gamma[c0];
  *(float4*)&g[4] = *(const float4*)&gamma[c0 + 4];
  *(float4*)&b[0] = *(const float4*)&beta[c0];
  *(float4*)&b[4] = *(const float4*)&beta[c0 + 4];
  alignas(16) bf16_t o8[8];
#pragma unroll
  for (int i = 0; i < 8; ++i)
    o8[i] = __float2bfloat16((v[i] - m) * inv * g[i] + b[i]);
  *(uint4*)&yrow[c0] = *(const uint4*)o8;
}

// x -> LN -> y (bf16). one wave per row.
__global__ void ln_kernel(const float* __restrict__ Xin,
                          const float* __restrict__ gamma,
                          const float* __restrict__ beta,
                          bf16_t* __restrict__ Y)
{
  const int row  = blockIdx.x;
  const int lane = threadIdx.x;
  const float* xr = Xin + (size_t)row * D_;
  const int c0 = lane * 8;
  float v[8];
  *(float4*)&v[0] = *(const float4*)&xr[c0];
  *(float4*)&v[4] = *(const float4*)&xr[c0 + 4];
  ln_store(v, gamma, beta, Y + (size_t)row * D_, lane);
}

// x = bit_emb[a]+bit_emb[b] + h ; y = LN1_0(x). one wave per row.
// hsrc/hstride: t==0 -> (start_state, 0); else -> (X, D_)
__global__ void add_ln_kernel(const int* __restrict__ a_seq,
                              const int* __restrict__ b_seq,
                              const float* __restrict__ bit_emb,
                              const float* __restrict__ hsrc, int hstride,
                              float* __restrict__ X,
                              const float* __restrict__ gamma,
                              const float* __restrict__ beta,
                              bf16_t* __restrict__ Y, int t)
{
  const int row  = blockIdx.x;
  const int lane = threadIdx.x;
  const int ai = a_seq[row * S_ + t];
  const int bi = b_seq[row * S_ + t];
  const int c0 = lane * 8;
  float* xr = X + (size_t)row * D_;
  const float* pr = hsrc + (size_t)row * hstride + c0;
  float ea[8], eb[8], p[8], v[8];
  *(float4*)&ea[0] = *(const float4*)&bit_emb[ai * D_ + c0];
  *(float4*)&ea[4] = *(const float4*)&bit_emb[ai * D_ + c0 + 4];
  *(float4*)&eb[0] = *(const float4*)&bit_emb[bi * D_ + c0];
  *(float4*)&eb[4] = *(const float4*)&bit_emb[bi * D_ + c0 + 4];
  *(float4*)&p[0]  = *(const float4*)&pr[0];
  *(float4*)&p[4]  = *(const float4*)&pr[4];
#pragma unroll
  for (int i = 0; i < 8; ++i) v[i] = ea[i] + eb[i] + p[i];
  *(float4*)&xr[c0]     = *(const float4*)&v[0];
  *(float4*)&xr[c0 + 4] = *(const float4*)&v[4];
  ln_store(v, gamma, beta, Y + (size_t)row * D_, lane);
}

// logits[b,t,:] = x @ head_w(512x2) + head_b. one wave per row.
__global__ void head_kernel(const float* __restrict__ X,
                            const float* __restrict__ hw,
                            const float* __restrict__ hb,
                            float* __restrict__ out, int t)
{
  const int row  = blockIdx.x;
  const int lane = threadIdx.x;
  const float* xr = X + (size_t)row * D_;
  const int c0 = lane * 8;
  float v[8];
  *(float4*)&v[0] = *(const float4*)&xr[c0];
  *(float4*)&v[4] = *(const float4*)&xr[c0 + 4];
  float w[16];
#pragma unroll
  for (int i = 0; i < 4; ++i)
    *(float4*)&w[i * 4] = *(const float4*)&hw[lane * 16 + i * 4];
  float s0 = 0.f, s1 = 0.f;
#pragma unroll
  for (int i = 0; i < 8; ++i) { s0 += v[i] * w[2 * i]; s1 += v[i] * w[2 * i + 1]; }
#pragma unroll
  for (int o = 32; o; o >>= 1) { s0 += __shfl_xor(s0, o); s1 += __shfl_xor(s1, o); }
  if (lane == 0) {
    float* po = out + (size_t)row * (S_ * 2) + t * 2;
    po[0] = s0 + hb[0];
    po[1] = s1 + hb[1];
  }
}

// ---------------------------------------------------------------------------
// Prep kernels (run every launch; graph-safe)
// ---------------------------------------------------------------------------
// Wc[l][k][n] = sum_j qkv_w[l][k][2D+j] * out_w[l][j][n]   (fp32)
__global__ void prep_wc(const float* __restrict__ qkv_w,
                        const float* __restrict__ out_w,
                        float* __restrict__ wc)
{
  const int n = blockIdx.x * 256 + threadIdx.x;
  const int k = blockIdx.y;
  const int l = blockIdx.z;
  const float* qrow = qkv_w + ((size_t)l * D_ + k) * (3 * D_) + 2 * D_;
  const float* ow   = out_w + (size_t)l * D_ * D_;
  float acc = 0.f;
  for (int j = 0; j < D_; ++j) acc += qrow[j] * ow[(size_t)j * D_ + n];
  wc[((size_t)l * D_ + k) * D_ + n] = acc;
}

// bc[l][n] = qkv_b[l][2D:] @ out_w[l][:, n] + out_b[l][n]
__global__ void prep_bc(const float* __restrict__ qkv_b,
                        const float* __restrict__ out_w,
                        const float* __restrict__ out_b,
                        float* __restrict__ bc)
{
  const int l = blockIdx.x;
  const int n = threadIdx.x;
  const float* qb = qkv_b + (size_t)l * (3 * D_) + 2 * D_;
  const float* ow = out_w + (size_t)l * D_ * D_;
  float acc = out_b[(size_t)l * D_ + n];
  for (int j = 0; j < D_; ++j) acc += qb[j] * ow[(size_t)j * D_ + n];
  bc[(size_t)l * D_ + n] = acc;
}

// dst(C,R) bf16 = transpose(src(R,C) fp32), per-layer via blockIdx.z
__global__ void transpose_conv(const float* __restrict__ src,
                               bf16_t* __restrict__ dst, int R, int C)
{
  __shared__ float tile[32][33];
  const int l = blockIdx.z;
  const float* s = src + (size_t)l * R * C;
  bf16_t* d = dst + (size_t)l * R * C;
  const int c0 = blockIdx.x * 32, r0 = blockIdx.y * 32;
  const int tx = threadIdx.x, ty = threadIdx.y;
  tile[ty][tx] = s[(size_t)(r0 + ty) * C + (c0 + tx)];
  __syncthreads();
  d[(size_t)(c0 + ty) * R + (r0 + tx)] = __float2bfloat16(tile[tx][ty]);
}

// ---------------------------------------------------------------------------
extern "C" void kernel_launch(void* const* d_in, const int* in_sizes, int n_in,
                              void* d_out, int out_size, void* d_ws, size_t ws_size,
                              hipStream_t stream)
{
  const int*   a_seq     = (const int*)  d_in[0];
  const int*   b_seq     = (const int*)  d_in[1];
  const float* bit_emb   = (const float*)d_in[2];
  const float* start     = (const float*)d_in[3];
  const float* ln1_g     = (const float*)d_in[4];
  const float* ln1_b     = (const float*)d_in[5];
  const float* qkv_w     = (const float*)d_in[6];
  const float* qkv_b     = (const float*)d_in[7];
  const float* out_w     = (const float*)d_in[8];
  const float* out_b     = (const float*)d_in[9];
  const float* ln2_g     = (const float*)d_in[10];
  const float* ln2_b     = (const float*)d_in[11];
  const float* ff1_w     = (const float*)d_in[12];
  const float* ff1_b     = (const float*)d_in[13];
  const float* ff2_w     = (const float*)d_in[14];
  const float* ff2_b     = (const float*)d_in[15];
  const float* head_w    = (const float*)d_in[16];
  const float* head_b    = (const float*)d_in[17];
  float* out = (float*)d_out;

  // workspace layout
  char* ws = (char*)d_ws;
  float*  X     = (float*) ws; ws += (size_t)B_ * D_ * 4;            // 8 MB
  bf16_t* Y     = (bf16_t*)ws; ws += (size_t)B_ * D_ * 2;            // 4 MB
  bf16_t* U     = (bf16_t*)ws; ws += (size_t)B_ * 4 * D_ * 2;        // 16 MB
  bf16_t* WCT   = (bf16_t*)ws; ws += (size_t)DEPTH_ * D_ * D_ * 2;   // 2 MB
  bf16_t* FF1T  = (bf16_t*)ws; ws += (size_t)DEPTH_ * D_ * 4 * D_ * 2; // 8 MB
  bf16_t* FF2T  = (bf16_t*)ws; ws += (size_t)DEPTH_ * 4 * D_ * D_ * 2; // 8 MB
  float*  BC    = (float*) ws; ws += (size_t)DEPTH_ * D_ * 4;        // 8 KB
  float*  WCTMP = (float*) ws; ws += (size_t)DEPTH_ * D_ * D_ * 4;   // 4 MB

  // ---- weight prep (per launch, identical every call) ----
  prep_wc<<<dim3(2, 512, 4), 256, 0, stream>>>(qkv_w, out_w, WCTMP);
  prep_bc<<<4, 512, 0, stream>>>(qkv_b, out_w, out_b, BC);
  transpose_conv<<<dim3(16, 16, 4),  dim3(32, 32), 0, stream>>>(WCTMP, WCT, 512, 512);
  transpose_conv<<<dim3(64, 16, 4),  dim3(32, 32), 0, stream>>>(ff1_w, FF1T, 512, 2048);
  transpose_conv<<<dim3(16, 64, 4),  dim3(32, 32), 0, stream>>>(ff2_w, FF2T, 2048, 512);

  // ---- recurrent steps ----
  for (int t = 0; t < S_; ++t) {
    if (t == 0)
      add_ln_kernel<<<B_, 64, 0, stream>>>(a_seq, b_seq, bit_emb, start, 0,
                                           X, ln1_g, ln1_b, Y, t);
    else
      add_ln_kernel<<<B_, 64, 0, stream>>>(a_seq, b_seq, bit_emb, X, D_,
                                           X, ln1_g, ln1_b, Y, t);
    for (int l = 0; l < DEPTH_; ++l) {
      // x += y @ Wc[l] + bc[l]
      gemm_bf16<64, 64, 0><<<dim3(64, 8), 256, 0, stream>>>(
          Y, WCT + (size_t)l * D_ * D_, BC + (size_t)l * D_, X, nullptr,
          B_, D_, D_);
      // y = LN2(x)
      ln_kernel<<<B_, 64, 0, stream>>>(X, ln2_g + (size_t)l * D_, ln2_b + (size_t)l * D_, Y);
      // u = relu(y @ ff1[l] + b1)
      gemm_bf16<128, 128, 1><<<dim3(32, 16), 256, 0, stream>>>(
          Y, FF1T + (size_t)l * D_ * 4 * D_, ff1_b + (size_t)l * 4 * D_, nullptr, U,
          B_, 4 * D_, D_);
      // x += u @ ff2[l] + b2
      gemm_bf16<64, 64, 0><<<dim3(64, 8), 256, 0, stream>>>(
          U, FF2T + (size_t)l * 4 * D_ * D_, ff2_b + (size_t)l * D_, X, nullptr,
          B_, D_, 4 * D_);
      // y = LN1[l+1](x) for next layer
      if (l < DEPTH_ - 1)
        ln_kernel<<<B_, 64, 0, stream>>>(X, ln1_g + (size_t)(l + 1) * D_,
                                         ln1_b + (size_t)(l + 1) * D_, Y);
    }
    head_kernel<<<B_, 64, 0, stream>>>(X, head_w, head_b, out, t);
  }
}